// Round 3
// baseline (191.144 us; speedup 1.0000x reference)
//
#include <hip/hip_runtime.h>
#include <math.h>

// x: (8, 32, 512, 512) f32 -> (dilated = 3x3 max, eroded = 3x3 min), 'same',
// borders reduce over valid pixels only (identity padding with -inf/+inf).
// 256 planes of 512x512.
//
// One wave (64 lanes) owns a full 512-px row strip: lane l covers pixels
// [8l, 8l+8). Horizontal halo via __shfl_up/__shfl_down (no edge loads).
// Each wave computes 16 output rows (rolling 3-row window) -> vertical read
// redundancy 18/16 = 1.125x. Traffic ~= 288 MB read + 512 MB write.

#define IMG_W 512
#define IMG_H 512
#define PLANE (IMG_W * IMG_H)
#define ROWS_PER_WAVE 16

struct HRow {
    float4 xa, xb;  // horizontal 3-max for elems 0-3, 4-7
    float4 na, nb;  // horizontal 3-min
};

__device__ __forceinline__ HRow load_hrow(const float* __restrict__ row,
                                          int x0, int lane) {
    const float4 a = *reinterpret_cast<const float4*>(row + x0);
    const float4 b = *reinterpret_cast<const float4*>(row + x0 + 4);

    // neighbor halo: left = lane-1's b.w, right = lane+1's a.x
    const float lv = __shfl_up(b.w, 1);
    const float rv = __shfl_down(a.x, 1);
    const float lmax = (lane == 0)  ? -INFINITY : lv;
    const float lmin = (lane == 0)  ?  INFINITY : lv;
    const float rmax = (lane == 63) ? -INFINITY : rv;
    const float rmin = (lane == 63) ?  INFINITY : rv;

    HRow h;
    h.xa.x = fmaxf(fmaxf(lmax, a.x), a.y);
    h.xa.y = fmaxf(fmaxf(a.x,  a.y), a.z);
    h.xa.z = fmaxf(fmaxf(a.y,  a.z), a.w);
    h.xa.w = fmaxf(fmaxf(a.z,  a.w), b.x);
    h.xb.x = fmaxf(fmaxf(a.w,  b.x), b.y);
    h.xb.y = fmaxf(fmaxf(b.x,  b.y), b.z);
    h.xb.z = fmaxf(fmaxf(b.y,  b.z), b.w);
    h.xb.w = fmaxf(fmaxf(b.z,  b.w), rmax);

    h.na.x = fminf(fminf(lmin, a.x), a.y);
    h.na.y = fminf(fminf(a.x,  a.y), a.z);
    h.na.z = fminf(fminf(a.y,  a.z), a.w);
    h.na.w = fminf(fminf(a.z,  a.w), b.x);
    h.nb.x = fminf(fminf(a.w,  b.x), b.y);
    h.nb.y = fminf(fminf(b.x,  b.y), b.z);
    h.nb.z = fminf(fminf(b.y,  b.z), b.w);
    h.nb.w = fminf(fminf(b.z,  b.w), rmin);
    return h;
}

__device__ __forceinline__ HRow inf_hrow() {
    HRow h;
    h.xa = make_float4(-INFINITY, -INFINITY, -INFINITY, -INFINITY);
    h.xb = h.xa;
    h.na = make_float4( INFINITY,  INFINITY,  INFINITY,  INFINITY);
    h.nb = h.na;
    return h;
}

__global__ __launch_bounds__(256) void erode_dilate_kernel(
    const float* __restrict__ x,
    float* __restrict__ dil,
    float* __restrict__ ero)
{
    const int tid  = blockIdx.x * blockDim.x + threadIdx.x;
    const int lane = tid & 63;
    const int wid  = tid >> 6;          // global wave id
    const int rg   = wid & 31;          // row-group 0..31 (16 rows each)
    const int p    = wid >> 5;          // plane 0..255

    const int x0 = lane << 3;           // 0..504
    const int y0 = rg << 4;             // 0,16,...,496

    const float* plane = x + (size_t)p * PLANE;

    // Rolling 3-row window of horizontal results.
    HRow h0, h1, h2;
    h0 = (y0 > 0) ? load_hrow(plane + (size_t)(y0 - 1) * IMG_W, x0, lane)
                  : inf_hrow();
    h1 = load_hrow(plane + (size_t)y0 * IMG_W, x0, lane);

    size_t o = (size_t)p * PLANE + (size_t)y0 * IMG_W + x0;

    #pragma unroll
    for (int r = 0; r < ROWS_PER_WAVE; ++r) {
        const int yy = y0 + r + 1;
        h2 = (yy < IMG_H) ? load_hrow(plane + (size_t)yy * IMG_W, x0, lane)
                          : inf_hrow();

        float4 da, db, ea, eb;
        da.x = fmaxf(fmaxf(h0.xa.x, h1.xa.x), h2.xa.x);
        da.y = fmaxf(fmaxf(h0.xa.y, h1.xa.y), h2.xa.y);
        da.z = fmaxf(fmaxf(h0.xa.z, h1.xa.z), h2.xa.z);
        da.w = fmaxf(fmaxf(h0.xa.w, h1.xa.w), h2.xa.w);
        db.x = fmaxf(fmaxf(h0.xb.x, h1.xb.x), h2.xb.x);
        db.y = fmaxf(fmaxf(h0.xb.y, h1.xb.y), h2.xb.y);
        db.z = fmaxf(fmaxf(h0.xb.z, h1.xb.z), h2.xb.z);
        db.w = fmaxf(fmaxf(h0.xb.w, h1.xb.w), h2.xb.w);

        ea.x = fminf(fminf(h0.na.x, h1.na.x), h2.na.x);
        ea.y = fminf(fminf(h0.na.y, h1.na.y), h2.na.y);
        ea.z = fminf(fminf(h0.na.z, h1.na.z), h2.na.z);
        ea.w = fminf(fminf(h0.na.w, h1.na.w), h2.na.w);
        eb.x = fminf(fminf(h0.nb.x, h1.nb.x), h2.nb.x);
        eb.y = fminf(fminf(h0.nb.y, h1.nb.y), h2.nb.y);
        eb.z = fminf(fminf(h0.nb.z, h1.nb.z), h2.nb.z);
        eb.w = fminf(fminf(h0.nb.w, h1.nb.w), h2.nb.w);

        *reinterpret_cast<float4*>(dil + o)     = da;
        *reinterpret_cast<float4*>(dil + o + 4) = db;
        *reinterpret_cast<float4*>(ero + o)     = ea;
        *reinterpret_cast<float4*>(ero + o + 4) = eb;
        o += IMG_W;

        h0 = h1;
        h1 = h2;
    }
}

extern "C" void kernel_launch(void* const* d_in, const int* in_sizes, int n_in,
                              void* d_out, int out_size, void* d_ws, size_t ws_size,
                              hipStream_t stream) {
    const float* x = (const float*)d_in[0];
    float* out = (float*)d_out;

    const size_t n_elems = (size_t)8 * 32 * 512 * 512;  // 67,108,864
    float* dil = out;
    float* ero = out + n_elems;

    // waves: 256 planes * 32 row-groups = 8192 waves -> 524288 threads
    const int total_threads = 8192 * 64;
    const int block = 256;
    const int grid = total_threads / block;   // 2048

    erode_dilate_kernel<<<grid, block, 0, stream>>>(x, dil, ero);
}

// Round 5
// 128.719 us; speedup vs baseline: 1.4850x; 1.4850x over previous
//
#include <hip/hip_runtime.h>
#include <math.h>

// x: (8, 32, 512, 512) f32 -> (dilated = 3x3 max, eroded = 3x3 min), 'same',
// borders reduce over valid pixels only (identity padding with -inf/+inf).
// 256 planes of 512x512.
//
// Layout: 4 px/lane, wave = 64 lanes = 256 contiguous px (half a row).
// Horizontal halo via __shfl_up/__shfl_down; only lanes 0/63 do a scalar
// edge load (L1-cheap). Stores: each wave writes 1 KB contiguous per row per
// output, non-temporal (outputs are pure streams - keep them out of L2/L3).
// 16 output rows per thread -> vertical read redundancy 18/16 = 1.125x.

#define IMG_W 512
#define IMG_H 512
#define PLANE (IMG_W * IMG_H)
#define ROWS_PER_THREAD 16

typedef float f32x4 __attribute__((ext_vector_type(4)));  // native vec for nt-store

struct HRow {
    float4 hx;  // horizontal 3-max for the 4 pixels
    float4 hn;  // horizontal 3-min
};

__device__ __forceinline__ HRow load_hrow(const float* __restrict__ row,
                                          int x0, int lane) {
    const float4 v = *reinterpret_cast<const float4*>(row + x0);

    // halo from neighbor lanes
    float lv = __shfl_up(v.w, 1);    // lane-1's last pixel = row[x0-1]
    float rv = __shfl_down(v.x, 1);  // lane+1's first pixel = row[x0+4]

    float lmax, lmin, rmax, rmin;
    if (lane == 0) {
        if (x0 > 0) { const float l = row[x0 - 1]; lmax = l; lmin = l; }
        else        { lmax = -INFINITY; lmin = INFINITY; }
    } else { lmax = lv; lmin = lv; }
    if (lane == 63) {
        if (x0 + 4 < IMG_W) { const float r = row[x0 + 4]; rmax = r; rmin = r; }
        else                { rmax = -INFINITY; rmin = INFINITY; }
    } else { rmax = rv; rmin = rv; }

    HRow h;
    h.hx.x = fmaxf(fmaxf(lmax, v.x), v.y);
    h.hx.y = fmaxf(fmaxf(v.x,  v.y), v.z);
    h.hx.z = fmaxf(fmaxf(v.y,  v.z), v.w);
    h.hx.w = fmaxf(fmaxf(v.z,  v.w), rmax);
    h.hn.x = fminf(fminf(lmin, v.x), v.y);
    h.hn.y = fminf(fminf(v.x,  v.y), v.z);
    h.hn.z = fminf(fminf(v.y,  v.z), v.w);
    h.hn.w = fminf(fminf(v.z,  v.w), rmin);
    return h;
}

__device__ __forceinline__ HRow inf_hrow() {
    HRow h;
    h.hx = make_float4(-INFINITY, -INFINITY, -INFINITY, -INFINITY);
    h.hn = make_float4( INFINITY,  INFINITY,  INFINITY,  INFINITY);
    return h;
}

__global__ __launch_bounds__(256) void erode_dilate_kernel(
    const float* __restrict__ x,
    float* __restrict__ dil,
    float* __restrict__ ero)
{
    const int tid  = blockIdx.x * blockDim.x + threadIdx.x;
    const int lane = threadIdx.x & 63;
    const int x0   = (tid & 127) << 2;         // 0..508 (quad)
    const int y0   = ((tid >> 7) & 31) << 4;   // 0,16,...,496
    const int p    = tid >> 12;                // plane 0..255

    const float* plane = x + (size_t)p * PLANE;

    HRow h0, h1, h2;
    h0 = (y0 > 0) ? load_hrow(plane + (size_t)(y0 - 1) * IMG_W, x0, lane)
                  : inf_hrow();
    h1 = load_hrow(plane + (size_t)y0 * IMG_W, x0, lane);

    size_t o = (size_t)p * PLANE + (size_t)y0 * IMG_W + x0;

    #pragma unroll
    for (int r = 0; r < ROWS_PER_THREAD; ++r) {
        const int yy = y0 + r + 1;
        h2 = (yy < IMG_H) ? load_hrow(plane + (size_t)yy * IMG_W, x0, lane)
                          : inf_hrow();

        f32x4 d, e;
        d.x = fmaxf(fmaxf(h0.hx.x, h1.hx.x), h2.hx.x);
        d.y = fmaxf(fmaxf(h0.hx.y, h1.hx.y), h2.hx.y);
        d.z = fmaxf(fmaxf(h0.hx.z, h1.hx.z), h2.hx.z);
        d.w = fmaxf(fmaxf(h0.hx.w, h1.hx.w), h2.hx.w);
        e.x = fminf(fminf(h0.hn.x, h1.hn.x), h2.hn.x);
        e.y = fminf(fminf(h0.hn.y, h1.hn.y), h2.hn.y);
        e.z = fminf(fminf(h0.hn.z, h1.hn.z), h2.hn.z);
        e.w = fminf(fminf(h0.hn.w, h1.hn.w), h2.hn.w);

        __builtin_nontemporal_store(d, reinterpret_cast<f32x4*>(dil + o));
        __builtin_nontemporal_store(e, reinterpret_cast<f32x4*>(ero + o));
        o += IMG_W;

        h0 = h1;
        h1 = h2;
    }
}

extern "C" void kernel_launch(void* const* d_in, const int* in_sizes, int n_in,
                              void* d_out, int out_size, void* d_ws, size_t ws_size,
                              hipStream_t stream) {
    const float* x = (const float*)d_in[0];
    float* out = (float*)d_out;

    const size_t n_elems = (size_t)8 * 32 * 512 * 512;  // 67,108,864
    float* dil = out;
    float* ero = out + n_elems;

    // threads: 128 per row-strip x 32 row-groups x 256 planes = 1,048,576
    const int total_threads = (int)(n_elems / (4 * ROWS_PER_THREAD));
    const int block = 256;
    const int grid = total_threads / block;   // 4096

    erode_dilate_kernel<<<grid, block, 0, stream>>>(x, dil, ero);
}